// Round 2
// baseline (324.298 us; speedup 1.0000x reference)
//
#include <hip/hip_runtime.h>
#include <hip/hip_bf16.h>
#include <stdint.h>

// Problem constants (B,T,C) = (4,4096,1024)
#define TT 4096
#define BB 4
#define CC 1024
#define MM (BB * TT)          // 16384 rows
#define NCHUNK 64             // scan chunks along T
#define CHUNK_T (TT / NCHUNK) // 64 steps per chunk
#define NCHAIN (BB * CC)      // 4096 independent scan chains

typedef float f32x4 __attribute__((ext_vector_type(4)));
typedef __bf16 bf16x8 __attribute__((ext_vector_type(8)));

__device__ __forceinline__ float b2f(ushort u) {
  union { float f; uint32_t v; } x; x.v = ((uint32_t)u) << 16; return x.f;
}
__device__ __forceinline__ ushort f2b(float f) { // RNE fp32->bf16
  union { float f; uint32_t u; } x; x.f = f;
  uint32_t r = x.u + 0x7fffu + ((x.u >> 16) & 1u);
  return (ushort)(r >> 16);
}

// async global->LDS, 16B per lane. LDS dest must be uniform-base + lane*16.
__device__ __forceinline__ void async_copy16(const ushort* g, ushort* l) {
  __builtin_amdgcn_global_load_lds(
      (__attribute__((address_space(1))) void*)(g),
      (__attribute__((address_space(3))) void*)(l), 16, 0, 0);
}

// One kernel converts x, Wf, Wg, Wp to bf16. Region sizes in float4 units:
// x: 4194304, each W: 262144. Total 4980736 = 19456 * 256 exactly.
__global__ __launch_bounds__(256) void cvt_all(const float* __restrict__ x,
                                               const float* __restrict__ wf,
                                               const float* __restrict__ wg,
                                               const float* __restrict__ wp,
                                               ushort* __restrict__ xb,
                                               ushort* __restrict__ wcat,
                                               ushort* __restrict__ wpb) {
  const int i = blockIdx.x * 256 + threadIdx.x;
  const float* s; ushort* d; int off;
  if (i < 4194304)            { s = x;  d = xb;              off = i; }
  else if (i < 4456448)       { s = wf; d = wcat;            off = i - 4194304; }
  else if (i < 4718592)       { s = wg; d = wcat + 1048576;  off = i - 4456448; }
  else                        { s = wp; d = wpb;             off = i - 4718592; }
  float4 v = ((const float4*)s)[off];
  ushort4 o;
  o.x = f2b(v.x); o.y = f2b(v.y); o.z = f2b(v.z); o.w = f2b(v.w);
  ((ushort4*)d)[off] = o;
}

// C[m][n] = sum_k A[m][k] * Bw[n][k]  (row-major, K=1024 contiguous)
// TM fixed 128, template TN (tile n) / WTN (wave tile n). 4 waves as 2x2.
// MODE 0: fp32 out. MODE 1: gates epilogue (n<1024 sigmoid, else tanh), bf16 out.
// LDS XOR swizzle: slot s of row r holds global k-chunk s ^ ((r>>1)&3).
template <int TN, int WTN, int MODE>
__global__ __launch_bounds__(256) void gemm_bt(const ushort* __restrict__ A,
                                               const ushort* __restrict__ Bw,
                                               float* __restrict__ outF,
                                               ushort* __restrict__ outB, int N) {
  constexpr int K = CC;
  constexpr int JN = WTN / 16;        // n-frags per wave
  constexpr int NCH = (128 + TN) / 16; // staging chunks (16 rows each)
  __shared__ __align__(16) ushort sA[128 * 32];
  __shared__ __align__(16) ushort sB[TN * 32];
  const int tid = threadIdx.x;
  const int lane = tid & 63;
  const int wid = tid >> 6;
  const int wm = wid >> 1, wn = wid & 1;
  const long m0 = (long)blockIdx.y * 128;
  const long n0 = (long)blockIdx.x * TN;

  f32x4 acc[4][JN];
#pragma unroll
  for (int i = 0; i < 4; ++i)
#pragma unroll
    for (int j = 0; j < JN; ++j) acc[i][j] = (f32x4){0.f, 0.f, 0.f, 0.f};

  // staging fetch: lane -> row = lane>>2, k-chunk = (lane&3) ^ ((lane>>3)&3)
  const int srow = lane >> 2;
  const int kcf = (lane & 3) ^ ((lane >> 3) & 3);
  const ushort* Ab = A + (m0 + srow) * K + kcf * 8;
  const ushort* Bb = Bw + (n0 + srow) * K + kcf * 8;
  // fragment read slot (same for A and B; row bits 1..2 come from lane&15)
  const int slot = (lane >> 4) ^ ((lane >> 1) & 3);
  const int rlo = lane & 15;

  for (int k0 = 0; k0 < K; k0 += 32) {
#pragma unroll
    for (int ch = wid; ch < NCH; ch += 4) {
      if (ch < 8) async_copy16(Ab + (long)ch * 16 * K + k0, &sA[ch * 512 + lane * 8]);
      else async_copy16(Bb + (long)(ch - 8) * 16 * K + k0, &sB[(ch - 8) * 512 + lane * 8]);
    }
    __syncthreads();

    bf16x8 af[4], bfr[JN];
#pragma unroll
    for (int i = 0; i < 4; ++i)
      af[i] = *(const bf16x8*)&sA[(wm * 64 + i * 16 + rlo) * 32 + slot * 8];
#pragma unroll
    for (int j = 0; j < JN; ++j)
      bfr[j] = *(const bf16x8*)&sB[(wn * WTN + j * 16 + rlo) * 32 + slot * 8];
#pragma unroll
    for (int i = 0; i < 4; ++i)
#pragma unroll
      for (int j = 0; j < JN; ++j)
        acc[i][j] = __builtin_amdgcn_mfma_f32_16x16x32_bf16(af[i], bfr[j], acc[i][j], 0, 0, 0);
    __syncthreads();
  }

  // C/D layout (m89-verified): col = lane&15, row = (lane>>4)*4 + r
  const int col = lane & 15;
  const int rq = lane >> 4;
#pragma unroll
  for (int i = 0; i < 4; ++i) {
#pragma unroll
    for (int j = 0; j < JN; ++j) {
      const long n = n0 + wn * WTN + j * 16 + col;
#pragma unroll
      for (int r = 0; r < 4; ++r) {
        const long m = m0 + wm * 64 + i * 16 + rq * 4 + r;
        float v = acc[i][j][r];
        if (MODE == 0) {
          outF[m * N + n] = v;
        } else {
          float act;
          if (n < CC) {
            act = 1.f / (1.f + __expf(-v));            // f = sigmoid
          } else {
            float e = __expf(2.f * v);                  // g = tanh
            act = (e - 1.f) / (e + 1.f);
          }
          outB[m * (long)N + n] = f2b(act);
        }
      }
    }
  }
}

// P layout: [m=b*T+t][0..1023]=f (bf16), [1024..2047]=g (bf16)
// Recurrence h_t = f*h + (1-f)*g. Two chains per thread (ushort2/float2).
__global__ __launch_bounds__(256) void scan_pass1(const ushort* __restrict__ P,
                                                  float* __restrict__ cA,
                                                  float* __restrict__ cB) {
  const int pc = blockIdx.x * 256 + threadIdx.x; // chain pair 0..2047
  const int chunk = blockIdx.y;
  const int b = pc >> 9, c2 = (pc & 511) * 2;
  const ushort2* p =
      (const ushort2*)(P + (size_t)(b * TT + chunk * CHUNK_T) * (2 * CC) + c2);
  float A0 = 1.f, A1 = 1.f, h0 = 0.f, h1 = 0.f;
#pragma unroll 4
  for (int i = 0; i < CHUNK_T; ++i) {
    const ushort2 fu = p[0];
    const ushort2 gu = p[CC / 2];
    p += CC;
    const float f0 = b2f(fu.x), f1 = b2f(fu.y);
    const float g0 = b2f(gu.x), g1 = b2f(gu.y);
    A0 *= f0; A1 *= f1;
    h0 = fmaf(f0, h0, (1.f - f0) * g0);
    h1 = fmaf(f1, h1, (1.f - f1) * g1);
  }
  ((float2*)(cA + chunk * NCHAIN + b * CC))[c2 >> 1] = (float2){A0, A1};
  ((float2*)(cB + chunk * NCHAIN + b * CC))[c2 >> 1] = (float2){h0, h1};
}

// Carry computed inline (scan over prior chunks' cA/cB), then fixup + write H.
__global__ __launch_bounds__(256) void scan_pass3(const ushort* __restrict__ P,
                                                  const float* __restrict__ cA,
                                                  const float* __restrict__ cB,
                                                  ushort* __restrict__ H) {
  const int pc = blockIdx.x * 256 + threadIdx.x;
  const int chunk = blockIdx.y;
  const int b = pc >> 9, c2 = (pc & 511) * 2;
  const int ci = b * CC + c2;
  float h0 = 0.f, h1 = 0.f;
  for (int j = 0; j < chunk; ++j) {
    const float2 a = *(const float2*)(cA + j * NCHAIN + ci);
    const float2 bb = *(const float2*)(cB + j * NCHAIN + ci);
    h0 = fmaf(a.x, h0, bb.x);
    h1 = fmaf(a.y, h1, bb.y);
  }
  const ushort2* p =
      (const ushort2*)(P + (size_t)(b * TT + chunk * CHUNK_T) * (2 * CC) + c2);
  ushort2* hp = (ushort2*)(H + (size_t)(b * TT + chunk * CHUNK_T) * CC + c2);
#pragma unroll 4
  for (int i = 0; i < CHUNK_T; ++i) {
    const ushort2 fu = p[0];
    const ushort2 gu = p[CC / 2];
    p += CC;
    const float f0 = b2f(fu.x), f1 = b2f(fu.y);
    const float g0 = b2f(gu.x), g1 = b2f(gu.y);
    h0 = fmaf(f0, h0, (1.f - f0) * g0);
    h1 = fmaf(f1, h1, (1.f - f1) * g1);
    *hp = (ushort2){f2b(h0), f2b(h1)};
    hp += CC / 2;
  }
}

extern "C" void kernel_launch(void* const* d_in, const int* in_sizes, int n_in,
                              void* d_out, int out_size, void* d_ws, size_t ws_size,
                              hipStream_t stream) {
  const float* x  = (const float*)d_in[0];
  const float* Wf = (const float*)d_in[1];
  const float* Wg = (const float*)d_in[2];
  const float* Wp = (const float*)d_in[3];

  // workspace layout (bytes); H aliases xb (xb dead after gates GEMM, stream-ordered)
  char* ws = (char*)d_ws;
  ushort* xb   = (ushort*)(ws);                                  // 33554432 B
  ushort* Hb   = xb;                                             // alias
  ushort* Wcat = (ushort*)(ws + 33554432);                       //  4194304 B (Wf||Wg)
  ushort* Wpb  = (ushort*)(ws + 33554432 + 4194304);             //  2097152 B
  ushort* P    = (ushort*)(ws + 33554432 + 4194304 + 2097152);   // 67108864 B (f||g bf16)
  char* tail   = ws + 33554432 + 4194304 + 2097152 + 67108864;
  float* cA    = (float*)(tail);                                 // 1 MiB
  float* cB    = (float*)(tail + 1048576);                       // 1 MiB
  (void)ws_size; (void)in_sizes; (void)n_in; (void)out_size;

  // 1) all fp32 -> bf16 conversions in one launch
  cvt_all<<<19456, 256, 0, stream>>>(x, Wf, Wg, Wp, xb, Wcat, Wpb);

  // 2) gates GEMM: [16384 x 2048] = xb @ Wcat^T, fused sigmoid/tanh -> P (bf16)
  dim3 g1(2 * CC / 128, MM / 128);
  gemm_bt<128, 64, 1><<<g1, 256, 0, stream>>>(xb, Wcat, nullptr, P, 2 * CC);

  // 3) chunked scan: pass1 per-chunk compose, pass3 inline-carry + fixup
  dim3 gs(NCHAIN / 2 / 256, NCHUNK);
  scan_pass1<<<gs, 256, 0, stream>>>(P, cA, cB);
  scan_pass3<<<gs, 256, 0, stream>>>(P, cA, cB, Hb);

  // 4) projection GEMM: out = H @ Wp^T (fp32), 128x64 tile -> 2048 blocks
  dim3 g3(CC / 64, MM / 128);
  gemm_bt<64, 32, 0><<<g3, 256, 0, stream>>>(Hb, Wpb, (float*)d_out, nullptr, CC);
}